// Round 10
// baseline (631.819 us; speedup 1.0000x reference)
//
#include <hip/hip_runtime.h>
#include <math.h>

#define N_NODES 50000
#define N_EDGES 800000
#define HEADS 4
#define N_GRAPHS 64
#define NEG_SLOPE 0.2f
#define LOG2E 1.4426950408889634f
#define SCAN_NB 196            // 196*256 = 50176 >= N_NODES
#define FEAT_NB 782            // ceil(50000/64)
#define EDGE_Q 200000          // N_EDGES/4: 4 edges per thread
#define EDGE_NB 782            // ceil(200000/256)

typedef __attribute__((ext_vector_type(8))) short bf16x8;
typedef __attribute__((ext_vector_type(4))) float f32x4;

// monotone float<->uint key for atomicMax-based segment max (pooling).
__device__ __forceinline__ unsigned fkey(float f) {
    unsigned u = __float_as_uint(f);
    return (u & 0x80000000u) ? ~u : (u | 0x80000000u);
}
__device__ __forceinline__ float kval(unsigned k) {
    unsigned u = (k & 0x80000000u) ? (k & 0x7FFFFFFFu) : ~k;
    return __uint_as_float(u);
}

// f32 -> bf16 (RNE), two packed into one uint (lo = first channel)
__device__ __forceinline__ unsigned short f2bf(float f) {
    unsigned u = __float_as_uint(f);
    u += 0x7FFFu + ((u >> 16) & 1u);
    return (unsigned short)(u >> 16);
}
__device__ __forceinline__ unsigned pack_bf2(float a, float b) {
    return (unsigned)f2bf(a) | ((unsigned)f2bf(b) << 16);
}

// cheap ELU: o>0 ? o : exp(o)-1 via exp2 (saves ~10 inst vs expm1f; abs err ~1e-8)
__device__ __forceinline__ float elu_fast(float o) {
    float e = exp2f(o * LOG2E) - 1.f;
    return o > 0.f ? o : e;
}

// ---------------- CSR build (counting sort by dst, rank-based) ----------------

// hist stays STANDALONE low-footprint: its returning atomics are latency-bound
// and need max occupancy (R8: fusing with MFMA feat dropped occ to 31%, 3x cost).
__global__ void hist_kernel(const int* __restrict__ dst, int* __restrict__ deg,
                            int* __restrict__ rank) {
    int i = blockIdx.x * 256 + threadIdx.x;
    if (i >= EDGE_Q) return;
    int e0 = i, e1 = i + EDGE_Q, e2 = i + 2 * EDGE_Q, e3 = i + 3 * EDGE_Q;
    int d0 = dst[e0], d1 = dst[e1], d2 = dst[e2], d3 = dst[e3];
    int r0 = atomicAdd(&deg[d0], 1);
    int r1 = atomicAdd(&deg[d1], 1);
    int r2 = atomicAdd(&deg[d2], 1);
    int r3 = atomicAdd(&deg[d3], 1);
    rank[e0] = r0; rank[e1] = r1; rank[e2] = r2; rank[e3] = r3;
}

__global__ void partial_kernel(const int* __restrict__ deg, int* __restrict__ partial) {
    int t = threadIdx.x, b = blockIdx.x;
    int i = b * 256 + t;
    int v = (i < N_NODES) ? deg[i] : 0;
    #pragma unroll
    for (int off = 1; off < 64; off <<= 1) v += __shfl_xor(v, off, 64);
    __shared__ int wsum[4];
    if ((t & 63) == 0) wsum[t >> 6] = v;
    __syncthreads();
    if (t == 0) partial[b] = wsum[0] + wsum[1] + wsum[2] + wsum[3];
}

__global__ void csr_offsets_kernel(const int* __restrict__ deg, const int* __restrict__ partial,
                                   int* __restrict__ row_start) {
    __shared__ int sb[SCAN_NB];
    __shared__ int wsumA[4];
    __shared__ int wsumB[4];
    int t = threadIdx.x, b = blockIdx.x;
    int lane = t & 63, w = t >> 6;
    {   // exclusive scan of partial -> sb
        int v = (t < SCAN_NB) ? partial[t] : 0;
        int incl = v;
        #pragma unroll
        for (int off = 1; off < 64; off <<= 1) {
            int u = __shfl_up(incl, off, 64);
            if (lane >= off) incl += u;
        }
        if (lane == 63) wsumA[w] = incl;
        __syncthreads();
        int woff = 0;
        #pragma unroll
        for (int k = 0; k < 4; ++k) if (k < w) woff += wsumA[k];
        if (t < SCAN_NB) sb[t] = woff + incl - v;
        __syncthreads();
    }
    int i = b * 256 + t;
    int v = (i < N_NODES) ? deg[i] : 0;
    int incl = v;
    #pragma unroll
    for (int off = 1; off < 64; off <<= 1) {
        int u = __shfl_up(incl, off, 64);
        if (lane >= off) incl += u;
    }
    if (lane == 63) wsumB[w] = incl;
    __syncthreads();
    int woff = sb[b];
    #pragma unroll
    for (int k = 0; k < 4; ++k) if (k < w) woff += wsumB[k];
    int excl = woff + incl - v;
    if (i < N_NODES) row_start[i] = excl;
    else if (i == N_NODES) row_start[i] = excl;   // == N_EDGES
}

__device__ __forceinline__ void scatter_body(int bid, const int* __restrict__ src,
                                             const int* __restrict__ dst,
                                             const int* __restrict__ rank,
                                             const int* __restrict__ row_start,
                                             int* __restrict__ csr_src) {
    int i = bid * 256 + threadIdx.x;
    if (i >= EDGE_Q) return;
    int e0 = i, e1 = i + EDGE_Q, e2 = i + 2 * EDGE_Q, e3 = i + 3 * EDGE_Q;
    int d0 = dst[e0], d1 = dst[e1], d2 = dst[e2], d3 = dst[e3];
    int k0 = rank[e0], k1 = rank[e1], k2 = rank[e2], k3 = rank[e3];
    int s0 = src[e0], s1 = src[e1], s2 = src[e2], s3 = src[e3];
    csr_src[row_start[d0] + k0] = s0;
    csr_src[row_start[d1] + k1] = s1;
    csr_src[row_start[d2] + k2] = s2;
    csr_src[row_start[d3] + k3] = s3;
}

// ---------------- node pipeline ----------------

// Pre-pack W into MFMA B-fragment lane order (bf16).
__device__ __forceinline__ void wfrag_body(const float* __restrict__ W,
                                           unsigned* __restrict__ wf, int slot) {
    int f = slot >> 6, l = slot & 63;
    int n = l & 15, q = l >> 4;
    int ct = f >> 2, kq = f & 3;
    int col = 16 * ct + n;
    int k0 = 32 * kq + 8 * q;
    uint4 o;
    o.x = pack_bf2(W[(k0 + 0) * 128 + col], W[(k0 + 1) * 128 + col]);
    o.y = pack_bf2(W[(k0 + 2) * 128 + col], W[(k0 + 3) * 128 + col]);
    o.z = pack_bf2(W[(k0 + 4) * 128 + col], W[(k0 + 5) * 128 + col]);
    o.w = pack_bf2(W[(k0 + 6) * 128 + col], W[(k0 + 7) * 128 + col]);
    ((uint4*)wf)[slot] = o;
}

// prep: both W-frag packs + zero deg + zero pkeys, one launch.
__global__ void prep_kernel(const float* __restrict__ W0, const float* __restrict__ W1,
                            unsigned* __restrict__ wf0, unsigned* __restrict__ wf1,
                            int* __restrict__ deg, unsigned* __restrict__ pkeys) {
    int b = blockIdx.x, t = threadIdx.x;
    if (b < 8) {
        wfrag_body(W0, wf0, b * 256 + t);
    } else if (b < 16) {
        wfrag_body(W1, wf1, (b - 8) * 256 + t);
    } else if (b < 16 + SCAN_NB) {
        int i = (b - 16) * 256 + t;
        if (i < N_NODES) deg[i] = 0;
    } else {
        int i = (b - 16 - SCAN_NB) * 256 + t;
        if (i < N_GRAPHS * 128) pkeys[i] = 0;
    }
}

// feat = h @ W via MFMA 16x16x32 bf16. 64 nodes/block, 4 waves.
// featb NODE-major: featb[node*64 + ct*8 + pair] (bf16 channel pairs).
template<int IN_BF16>
__device__ __forceinline__ void feat_body(int bid, const void* __restrict__ hin,
                                          const int* __restrict__ wid,
                                          const unsigned* __restrict__ wf,
                                          const float* __restrict__ al,
                                          const float* __restrict__ ar,
                                          unsigned* __restrict__ featb,
                                          float* __restrict__ el, float* __restrict__ er) {
    __shared__ unsigned hl[64 * 68];     // 17408 B
    int t = threadIdx.x;
    int n0 = bid * 64;
    if (IN_BF16) {
        const uint4* hb4 = (const uint4*)hin;
        #pragma unroll
        for (int r = 0; r < 4; ++r) {    // 1024 uint4 = 64 nodes x 16
            int i = t + 256 * r;
            int n = i >> 4, q = i & 15;
            uint4 v = {0u, 0u, 0u, 0u};
            int gn = n0 + n;
            if (gn < N_NODES) v = hb4[(size_t)gn * 16 + q];
            *(uint4*)&hl[n * 68 + q * 4] = v;
        }
    } else {
        const float4* h4 = (const float4*)hin;
        #pragma unroll
        for (int r = 0; r < 8; ++r) {    // 2048 float4 = 64 nodes x 32
            int i = t + 256 * r;
            int n = i >> 5, q4 = i & 31;
            float4 v = {0.f, 0.f, 0.f, 0.f};
            int gn = n0 + n;
            if (gn < N_NODES) {
                int row = wid ? wid[gn] : gn;
                v = h4[(size_t)row * 32 + q4];
            }
            hl[n * 68 + q4 * 2]     = pack_bf2(v.x, v.y);
            hl[n * 68 + q4 * 2 + 1] = pack_bf2(v.z, v.w);
        }
    }
    __syncthreads();
    int w = t >> 6, lane = t & 63;
    int col = lane & 15, quad = lane >> 4;
    int nbase = n0 + 16 * w;
    bf16x8 afr[4];
    #pragma unroll
    for (int kq = 0; kq < 4; ++kq)
        afr[kq] = *(const bf16x8*)&hl[(16 * w + col) * 68 + 16 * kq + 4 * quad];
    f32x4 acc[8];
    #pragma unroll
    for (int ct = 0; ct < 8; ++ct) acc[ct] = (f32x4){0.f, 0.f, 0.f, 0.f};
    const uint4* wf4 = (const uint4*)wf;
    #pragma unroll
    for (int ct = 0; ct < 8; ++ct) {
        #pragma unroll
        for (int kq = 0; kq < 4; ++kq) {
            uint4 braw = wf4[(ct * 4 + kq) * 64 + lane];
            bf16x8 bfr = *(const bf16x8*)&braw;
            acc[ct] = __builtin_amdgcn_mfma_f32_16x16x32_bf16(afr[kq], bfr, acc[ct], 0, 0, 0);
        }
    }
    #pragma unroll
    for (int ct = 0; ct < 8; ++ct) {
        #pragma unroll
        for (int reg = 0; reg < 4; ++reg) {
            float v = acc[ct][reg];
            float pv = __shfl_xor(v, 1, 64);
            int node = nbase + quad * 4 + reg;
            if (!(col & 1) && node < N_NODES)
                featb[(size_t)node * 64 + ct * 8 + (col >> 1)] = pack_bf2(v, pv);
        }
    }
    float alv[8], arv[8];
    #pragma unroll
    for (int ct = 0; ct < 8; ++ct) {
        alv[ct] = al[ct * 16 + col];
        arv[ct] = ar[ct * 16 + col];
    }
    #pragma unroll
    for (int reg = 0; reg < 4; ++reg) {
        int node = nbase + quad * 4 + reg;
        #pragma unroll
        for (int hd = 0; hd < 4; ++hd) {
            float pl = acc[2 * hd][reg] * alv[2 * hd] + acc[2 * hd + 1][reg] * alv[2 * hd + 1];
            float pr = acc[2 * hd][reg] * arv[2 * hd] + acc[2 * hd + 1][reg] * arv[2 * hd + 1];
            #pragma unroll
            for (int off = 1; off < 16; off <<= 1) {
                pl += __shfl_xor(pl, off, 64);
                pr += __shfl_xor(pr, off, 64);
            }
            if (col == hd && node < N_NODES) {
                el[node * 4 + hd] = pl * LOG2E;
                er[node * 4 + hd] = pr * LOG2E;
            }
        }
    }
}

template<int IN_BF16>
__global__ __launch_bounds__(256)
void feat_kernel_t(const void* __restrict__ hin, const int* __restrict__ wid,
                   const unsigned* __restrict__ wf,
                   const float* __restrict__ al, const float* __restrict__ ar,
                   unsigned* __restrict__ featb, float* __restrict__ el,
                   float* __restrict__ er) {
    feat_body<IN_BF16>(blockIdx.x, hin, wid, wf, al, ar, featb, el, er);
}

// scatter (CSR finalize, no atomics) fused with full layer-0 feat (R7 structure).
__global__ __launch_bounds__(256)
void scatter_feat0_kernel(const int* __restrict__ src, const int* __restrict__ dst,
                          const int* __restrict__ rank, const int* __restrict__ row_start,
                          int* __restrict__ csr_src,
                          const float* __restrict__ emb, const int* __restrict__ wid,
                          const unsigned* __restrict__ wf0,
                          const float* __restrict__ al0, const float* __restrict__ ar0,
                          unsigned* __restrict__ featb, float* __restrict__ el,
                          float* __restrict__ er) {
    if (blockIdx.x < EDGE_NB) {
        scatter_body(blockIdx.x, src, dst, rank, row_start, csr_src);
    } else {
        feat_body<0>(blockIdx.x - EDGE_NB, emb, wid, wf0, al0, ar0, featb, el, er);
    }
}

// Fused softmax + aggregation + ELU. One 64-lane wave per dst node.
// 16 lanes per edge, 8-edge main loop (R7-proven; 16-edge unroll regressed —
// avg deg 16 means half the nodes would run entirely in the tail).
// OUT_BF16=1: write packed bf16 rows (layer 0 -> feat1 input).
// OUT_BF16=0 (layer 1): POOLING FUSED — epilogue atomicMax's the per-node
// channel values directly into pkeys (max is order-independent -> bit-identical
// to the old hout write + pool_kernel pass; saves 51 MB traffic + a kernel).
template<int OUT_BF16>
__global__ void gat_aggregate_t(const int* __restrict__ row_start, const int* __restrict__ csr_src,
                                const unsigned* __restrict__ featb, const float* __restrict__ el,
                                const float* __restrict__ er, const int* __restrict__ gid,
                                unsigned* __restrict__ pkeys, unsigned* __restrict__ houtb) {
    int lane = threadIdx.x & 63;
    int d = blockIdx.x * 4 + (threadIdx.x >> 6);
    int beg = row_start[d], end = row_start[d + 1];
    int eg = lane >> 4;          // edge slot 0..3
    int li = lane & 15;          // channel group: channels [8li, 8li+8)
    int hc = li >> 2;            // head of these channels
    float er_h = er[d * 4 + hc];
    float a0 = 0.f, a1 = 0.f, a2 = 0.f, a3 = 0.f;
    float a4 = 0.f, a5 = 0.f, a6 = 0.f, a7 = 0.f;
    float dsum = 0.f;
    int b8 = beg + ((end - beg) & ~7);
    for (int base = beg; base < b8; base += 8) {
        int ea = base + eg, eb = base + 4 + eg;
        int sa = csr_src[ea];
        int sb = csr_src[eb];
        float la = el[sa * 4 + hc];
        float lb = el[sb * 4 + hc];
        uint4 pa = *(const uint4*)(featb + (size_t)sa * 64 + li * 4);
        uint4 pb = *(const uint4*)(featb + (size_t)sb * 64 + li * 4);
        float va = la + er_h; va = fmaxf(va, NEG_SLOPE * va);
        float vb = lb + er_h; vb = fmaxf(vb, NEG_SLOPE * vb);
        float xa = exp2f(va), xb = exp2f(vb);
        dsum += xa + xb;
        a0 += __uint_as_float(pa.x << 16) * xa;
        a1 += __uint_as_float(pa.x & 0xFFFF0000u) * xa;
        a2 += __uint_as_float(pa.y << 16) * xa;
        a3 += __uint_as_float(pa.y & 0xFFFF0000u) * xa;
        a4 += __uint_as_float(pa.z << 16) * xa;
        a5 += __uint_as_float(pa.z & 0xFFFF0000u) * xa;
        a6 += __uint_as_float(pa.w << 16) * xa;
        a7 += __uint_as_float(pa.w & 0xFFFF0000u) * xa;
        a0 += __uint_as_float(pb.x << 16) * xb;
        a1 += __uint_as_float(pb.x & 0xFFFF0000u) * xb;
        a2 += __uint_as_float(pb.y << 16) * xb;
        a3 += __uint_as_float(pb.y & 0xFFFF0000u) * xb;
        a4 += __uint_as_float(pb.z << 16) * xb;
        a5 += __uint_as_float(pb.z & 0xFFFF0000u) * xb;
        a6 += __uint_as_float(pb.w << 16) * xb;
        a7 += __uint_as_float(pb.w & 0xFFFF0000u) * xb;
    }
    for (int ee = b8 + eg; ee < end; ee += 4) {
        int s = csr_src[ee];
        float lv = el[s * 4 + hc];
        uint4 pv = *(const uint4*)(featb + (size_t)s * 64 + li * 4);
        float v = lv + er_h; v = fmaxf(v, NEG_SLOPE * v);
        float x = exp2f(v);
        dsum += x;
        a0 += __uint_as_float(pv.x << 16) * x;
        a1 += __uint_as_float(pv.x & 0xFFFF0000u) * x;
        a2 += __uint_as_float(pv.y << 16) * x;
        a3 += __uint_as_float(pv.y & 0xFFFF0000u) * x;
        a4 += __uint_as_float(pv.z << 16) * x;
        a5 += __uint_as_float(pv.z & 0xFFFF0000u) * x;
        a6 += __uint_as_float(pv.w << 16) * x;
        a7 += __uint_as_float(pv.w & 0xFFFF0000u) * x;
    }
    #pragma unroll
    for (int off = 16; off < 64; off <<= 1) {
        a0 += __shfl_xor(a0, off, 64);
        a1 += __shfl_xor(a1, off, 64);
        a2 += __shfl_xor(a2, off, 64);
        a3 += __shfl_xor(a3, off, 64);
        a4 += __shfl_xor(a4, off, 64);
        a5 += __shfl_xor(a5, off, 64);
        a6 += __shfl_xor(a6, off, 64);
        a7 += __shfl_xor(a7, off, 64);
        dsum += __shfl_xor(dsum, off, 64);
    }
    if (eg == 0) {
        float inv = 1.f / (dsum + 1e-10f);
        float o0 = elu_fast(a0 * inv), o1 = elu_fast(a1 * inv);
        float o2 = elu_fast(a2 * inv), o3 = elu_fast(a3 * inv);
        float o4 = elu_fast(a4 * inv), o5 = elu_fast(a5 * inv);
        float o6 = elu_fast(a6 * inv), o7 = elu_fast(a7 * inv);
        if (OUT_BF16) {
            uint4 wv;
            wv.x = pack_bf2(o0, o1);
            wv.y = pack_bf2(o2, o3);
            wv.z = pack_bf2(o4, o5);
            wv.w = pack_bf2(o6, o7);
            ((uint4*)(houtb + (size_t)d * 64))[li] = wv;
        } else {
            int g = gid[d];
            unsigned* pk = pkeys + g * 128 + li * 8;
            atomicMax(&pk[0], fkey(o0));
            atomicMax(&pk[1], fkey(o1));
            atomicMax(&pk[2], fkey(o2));
            atomicMax(&pk[3], fkey(o3));
            atomicMax(&pk[4], fkey(o4));
            atomicMax(&pk[5], fkey(o5));
            atomicMax(&pk[6], fkey(o6));
            atomicMax(&pk[7], fkey(o7));
        }
    }
}

// ---------------- loss ----------------

// logits + loss fused: one block, 4 waves.
__global__ void logits_final_kernel(const unsigned* __restrict__ pkeys,
                                    const float* __restrict__ w, const float* __restrict__ bptr,
                                    const float* __restrict__ y, float* __restrict__ out) {
    __shared__ float slog[N_GRAPHS];
    int t = threadIdx.x;
    int wv = t >> 6, lane = t & 63;
    float b = bptr[0];
    #pragma unroll
    for (int k = 0; k < 16; ++k) {
        int g = wv * 16 + k;
        float sum = 0.f;
        #pragma unroll
        for (int c0 = 0; c0 < 128; c0 += 64) {
            int c = c0 + lane;
            unsigned kk = pkeys[g * 128 + c];
            float v = (kk == 0u) ? 0.f : kval(kk);
            sum += v * w[c];
        }
        #pragma unroll
        for (int off = 32; off; off >>= 1) sum += __shfl_down(sum, off, 64);
        if (lane == 0) slog[g] = sum + b;
    }
    __syncthreads();
    if (t < N_GRAPHS) {
        float l = slog[t];
        float term = fmaxf(l, 0.f) - l * y[t] + log1pf(expf(-fabsf(l)));
        float s = term;
        #pragma unroll
        for (int off = 32; off; off >>= 1) s += __shfl_down(s, off, 64);
        out[1 + t] = 1.f / (1.f + expf(-l));
        if (t == 0) out[0] = s * (1.f / 64.f);
    }
}

extern "C" void kernel_launch(void* const* d_in, const int* in_sizes, int n_in,
                              void* d_out, int out_size, void* d_ws, size_t ws_size,
                              hipStream_t stream) {
    const int* word_ids  = (const int*)d_in[0];
    const int* esrc      = (const int*)d_in[1];
    const int* edst      = (const int*)d_in[2];
    const int* gid       = (const int*)d_in[3];
    const float* y_data  = (const float*)d_in[4];
    const float* emb     = (const float*)d_in[5];
    const float* W0      = (const float*)d_in[6];
    const float* al0     = (const float*)d_in[7];
    const float* ar0     = (const float*)d_in[8];
    const float* W1      = (const float*)d_in[9];
    const float* al1     = (const float*)d_in[10];
    const float* ar1     = (const float*)d_in[11];
    const float* out_w   = (const float*)d_in[12];
    const float* out_b   = (const float*)d_in[13];
    float* out = (float*)d_out;

    // workspace layout (float offsets)
    float* ws = (float*)d_ws;
    unsigned* featb  = (unsigned*)ws;                // N*64 uints = 3,200,000
    unsigned* hb     = (unsigned*)(ws + 3200000);    // N*64 uints (bf16 layer0 out)
    float*    el     = ws + 6400000;                 // 200,000
    float*    er     = ws + 6600000;                 // 200,000
    int*      row_st = (int*)(ws + 6800000);         // 50,001 (pad to 50,004)
    int*      deg    = (int*)(ws + 6850004);         // 50,000
    int*      rank   = (int*)(ws + 6900004);         // 800,000
    int*      csrsrc = (int*)(ws + 7700004);         // 800,000
    int*      partial= (int*)(ws + 8500004);         // 196 (pad to 200)
    unsigned* pkeys  = (unsigned*)(ws + 8500204);    // 8,192
    unsigned* wf0    = (unsigned*)(ws + 8508396);    // 8,192 uints (16B-aligned)
    unsigned* wf1    = (unsigned*)(ws + 8516588);    // 8,192 uints

    // prep (W-frags, deg/pkeys zero) then CSR counting (standalone hist)
    prep_kernel<<<16 + SCAN_NB + 32, 256, 0, stream>>>(W0, W1, wf0, wf1, deg, pkeys);
    hist_kernel<<<EDGE_NB, 256, 0, stream>>>(edst, deg, rank);
    partial_kernel<<<SCAN_NB, 256, 0, stream>>>(deg, partial);
    csr_offsets_kernel<<<SCAN_NB, 256, 0, stream>>>(deg, partial, row_st);

    // CSR scatter (rank-based, no atomics) fused with full layer-0 feat
    scatter_feat0_kernel<<<EDGE_NB + FEAT_NB, 256, 0, stream>>>(
        esrc, edst, rank, row_st, csrsrc, emb, word_ids, wf0, al0, ar0, featb, el, er);

    // layer 0 aggregate -> packed bf16; layer 1 aggregate -> fused pooling
    gat_aggregate_t<1><<<12500, 256, 0, stream>>>(row_st, csrsrc, featb, el, er, nullptr, nullptr, hb);
    feat_kernel_t<1><<<FEAT_NB, 256, 0, stream>>>(hb, nullptr, wf1, al1, ar1, featb, el, er);
    gat_aggregate_t<0><<<12500, 256, 0, stream>>>(row_st, csrsrc, featb, el, er, gid, pkeys, nullptr);

    logits_final_kernel<<<1, 256, 0, stream>>>(pkeys, out_w, out_b, y_data, out);
}

// Round 11
// 272.552 us; speedup vs baseline: 2.3182x; 2.3182x over previous
//
#include <hip/hip_runtime.h>
#include <math.h>

#define N_NODES 50000
#define N_EDGES 800000
#define VOCAB 15000
#define HEADS 4
#define N_GRAPHS 64
#define NEG_SLOPE 0.2f
#define LOG2E 1.4426950408889634f
#define SCAN_NB 196            // 196*256 = 50176 >= N_NODES
#define POOL_CHUNK 50
#define POOL_NB 1000           // 1000*50 = 50000 exactly
#define FEAT_NB 782            // ceil(50000/64)
#define EDGE_Q 200000          // N_EDGES/4: 4 edges per thread
#define EDGE_NB 782            // ceil(200000/256)
#define EMB_NB 3750            // VOCAB*64 uints / 256

typedef __attribute__((ext_vector_type(8))) short bf16x8;
typedef __attribute__((ext_vector_type(4))) float f32x4;

// monotone float<->uint key for atomicMax-based segment max (pooling).
__device__ __forceinline__ unsigned fkey(float f) {
    unsigned u = __float_as_uint(f);
    return (u & 0x80000000u) ? ~u : (u | 0x80000000u);
}
__device__ __forceinline__ float kval(unsigned k) {
    unsigned u = (k & 0x80000000u) ? (k & 0x7FFFFFFFu) : ~k;
    return __uint_as_float(u);
}

// f32 -> bf16 (RNE), two packed into one uint (lo = first channel)
__device__ __forceinline__ unsigned short f2bf(float f) {
    unsigned u = __float_as_uint(f);
    u += 0x7FFFu + ((u >> 16) & 1u);
    return (unsigned short)(u >> 16);
}
__device__ __forceinline__ unsigned pack_bf2(float a, float b) {
    return (unsigned)f2bf(a) | ((unsigned)f2bf(b) << 16);
}

// cheap ELU: o>0 ? o : exp(o)-1 via exp2 (saves ~10 inst vs expm1f; abs err ~1e-8)
__device__ __forceinline__ float elu_fast(float o) {
    float e = exp2f(o * LOG2E) - 1.f;
    return o > 0.f ? o : e;
}

// ---------------- CSR build (counting sort by dst, rank-based) ----------------

// hist stays STANDALONE low-footprint: its returning atomics are latency-bound
// and need max occupancy (R8: fusing with MFMA feat dropped occ to 31%, 3x cost).
// R10 lesson: NEVER funnel high-multiplicity atomics into few addresses
// (fused pooling: 6.4M atomicMax on 8192 addrs -> 449us kernel).
__global__ void hist_kernel(const int* __restrict__ dst, int* __restrict__ deg,
                            int* __restrict__ rank) {
    int i = blockIdx.x * 256 + threadIdx.x;
    if (i >= EDGE_Q) return;
    int e0 = i, e1 = i + EDGE_Q, e2 = i + 2 * EDGE_Q, e3 = i + 3 * EDGE_Q;
    int d0 = dst[e0], d1 = dst[e1], d2 = dst[e2], d3 = dst[e3];
    int r0 = atomicAdd(&deg[d0], 1);
    int r1 = atomicAdd(&deg[d1], 1);
    int r2 = atomicAdd(&deg[d2], 1);
    int r3 = atomicAdd(&deg[d3], 1);
    rank[e0] = r0; rank[e1] = r1; rank[e2] = r2; rank[e3] = r3;
}

__global__ void partial_kernel(const int* __restrict__ deg, int* __restrict__ partial) {
    int t = threadIdx.x, b = blockIdx.x;
    int i = b * 256 + t;
    int v = (i < N_NODES) ? deg[i] : 0;
    #pragma unroll
    for (int off = 1; off < 64; off <<= 1) v += __shfl_xor(v, off, 64);
    __shared__ int wsum[4];
    if ((t & 63) == 0) wsum[t >> 6] = v;
    __syncthreads();
    if (t == 0) partial[b] = wsum[0] + wsum[1] + wsum[2] + wsum[3];
}

__global__ void csr_offsets_kernel(const int* __restrict__ deg, const int* __restrict__ partial,
                                   int* __restrict__ row_start) {
    __shared__ int sb[SCAN_NB];
    __shared__ int wsumA[4];
    __shared__ int wsumB[4];
    int t = threadIdx.x, b = blockIdx.x;
    int lane = t & 63, w = t >> 6;
    {   // exclusive scan of partial -> sb
        int v = (t < SCAN_NB) ? partial[t] : 0;
        int incl = v;
        #pragma unroll
        for (int off = 1; off < 64; off <<= 1) {
            int u = __shfl_up(incl, off, 64);
            if (lane >= off) incl += u;
        }
        if (lane == 63) wsumA[w] = incl;
        __syncthreads();
        int woff = 0;
        #pragma unroll
        for (int k = 0; k < 4; ++k) if (k < w) woff += wsumA[k];
        if (t < SCAN_NB) sb[t] = woff + incl - v;
        __syncthreads();
    }
    int i = b * 256 + t;
    int v = (i < N_NODES) ? deg[i] : 0;
    int incl = v;
    #pragma unroll
    for (int off = 1; off < 64; off <<= 1) {
        int u = __shfl_up(incl, off, 64);
        if (lane >= off) incl += u;
    }
    if (lane == 63) wsumB[w] = incl;
    __syncthreads();
    int woff = sb[b];
    #pragma unroll
    for (int k = 0; k < 4; ++k) if (k < w) woff += wsumB[k];
    int excl = woff + incl - v;
    if (i < N_NODES) row_start[i] = excl;
    else if (i == N_NODES) row_start[i] = excl;   // == N_EDGES
}

__device__ __forceinline__ void scatter_body(int bid, const int* __restrict__ src,
                                             const int* __restrict__ dst,
                                             const int* __restrict__ rank,
                                             const int* __restrict__ row_start,
                                             int* __restrict__ csr_src) {
    int i = bid * 256 + threadIdx.x;
    if (i >= EDGE_Q) return;
    int e0 = i, e1 = i + EDGE_Q, e2 = i + 2 * EDGE_Q, e3 = i + 3 * EDGE_Q;
    int d0 = dst[e0], d1 = dst[e1], d2 = dst[e2], d3 = dst[e3];
    int k0 = rank[e0], k1 = rank[e1], k2 = rank[e2], k3 = rank[e3];
    int s0 = src[e0], s1 = src[e1], s2 = src[e2], s3 = src[e3];
    csr_src[row_start[d0] + k0] = s0;
    csr_src[row_start[d1] + k1] = s1;
    csr_src[row_start[d2] + k2] = s2;
    csr_src[row_start[d3] + k3] = s3;
}

// ---------------- node pipeline ----------------

// Pre-pack W into MFMA B-fragment lane order (bf16).
__device__ __forceinline__ void wfrag_body(const float* __restrict__ W,
                                           unsigned* __restrict__ wf, int slot) {
    int f = slot >> 6, l = slot & 63;
    int n = l & 15, q = l >> 4;
    int ct = f >> 2, kq = f & 3;
    int col = 16 * ct + n;
    int k0 = 32 * kq + 8 * q;
    uint4 o;
    o.x = pack_bf2(W[(k0 + 0) * 128 + col], W[(k0 + 1) * 128 + col]);
    o.y = pack_bf2(W[(k0 + 2) * 128 + col], W[(k0 + 3) * 128 + col]);
    o.z = pack_bf2(W[(k0 + 4) * 128 + col], W[(k0 + 5) * 128 + col]);
    o.w = pack_bf2(W[(k0 + 6) * 128 + col], W[(k0 + 7) * 128 + col]);
    ((uint4*)wf)[slot] = o;
}

// prep: W-frag packs + zero deg/pkeys + PRE-PACK EMB TABLE TO BF16.
// feat0 rounds every gathered f32 to bf16 anyway (RNE) -> pre-rounding once is
// bit-identical, halves the random row-gather (512B -> 256B rows) and halves
// feat0's staging instruction count.
__global__ void prep_kernel(const float* __restrict__ W0, const float* __restrict__ W1,
                            const float* __restrict__ emb,
                            unsigned* __restrict__ wf0, unsigned* __restrict__ wf1,
                            unsigned* __restrict__ embb,
                            int* __restrict__ deg, unsigned* __restrict__ pkeys) {
    int b = blockIdx.x, t = threadIdx.x;
    if (b < 8) {
        wfrag_body(W0, wf0, b * 256 + t);
    } else if (b < 16) {
        wfrag_body(W1, wf1, (b - 8) * 256 + t);
    } else if (b < 16 + SCAN_NB) {
        int i = (b - 16) * 256 + t;
        if (i < N_NODES) deg[i] = 0;
    } else if (b < 16 + SCAN_NB + 32) {
        int i = (b - 16 - SCAN_NB) * 256 + t;
        if (i < N_GRAPHS * 128) pkeys[i] = 0;
    } else {
        int i = (b - 16 - SCAN_NB - 32) * 256 + t;     // 0 .. VOCAB*64-1
        if (i < VOCAB * 64) {
            int row = i >> 6, pr = i & 63;
            embb[i] = pack_bf2(emb[row * 128 + pr * 2], emb[row * 128 + pr * 2 + 1]);
        }
    }
}

// feat = h @ W via MFMA 16x16x32 bf16. 64 nodes/block, 4 waves.
// featb NODE-major: featb[node*64 + ct*8 + pair] (bf16 channel pairs).
// Input is always packed-bf16 rows of 16 uint4 (embb via wid gather, or hb direct).
__device__ __forceinline__ void feat_body(int bid, const unsigned* __restrict__ hin,
                                          const int* __restrict__ wid,
                                          const unsigned* __restrict__ wf,
                                          const float* __restrict__ al,
                                          const float* __restrict__ ar,
                                          unsigned* __restrict__ featb,
                                          float* __restrict__ el, float* __restrict__ er) {
    __shared__ unsigned hl[64 * 68];     // 17408 B
    int t = threadIdx.x;
    int n0 = bid * 64;
    const uint4* hb4 = (const uint4*)hin;
    #pragma unroll
    for (int r = 0; r < 4; ++r) {        // 1024 uint4 = 64 nodes x 16
        int i = t + 256 * r;
        int n = i >> 4, q = i & 15;
        uint4 v = {0u, 0u, 0u, 0u};
        int gn = n0 + n;
        if (gn < N_NODES) {
            int row = wid ? wid[gn] : gn;
            v = hb4[(size_t)row * 16 + q];
        }
        *(uint4*)&hl[n * 68 + q * 4] = v;
    }
    __syncthreads();
    int w = t >> 6, lane = t & 63;
    int col = lane & 15, quad = lane >> 4;
    int nbase = n0 + 16 * w;
    bf16x8 afr[4];
    #pragma unroll
    for (int kq = 0; kq < 4; ++kq)
        afr[kq] = *(const bf16x8*)&hl[(16 * w + col) * 68 + 16 * kq + 4 * quad];
    f32x4 acc[8];
    #pragma unroll
    for (int ct = 0; ct < 8; ++ct) acc[ct] = (f32x4){0.f, 0.f, 0.f, 0.f};
    const uint4* wf4 = (const uint4*)wf;
    #pragma unroll
    for (int ct = 0; ct < 8; ++ct) {
        #pragma unroll
        for (int kq = 0; kq < 4; ++kq) {
            uint4 braw = wf4[(ct * 4 + kq) * 64 + lane];
            bf16x8 bfr = *(const bf16x8*)&braw;
            acc[ct] = __builtin_amdgcn_mfma_f32_16x16x32_bf16(afr[kq], bfr, acc[ct], 0, 0, 0);
        }
    }
    #pragma unroll
    for (int ct = 0; ct < 8; ++ct) {
        #pragma unroll
        for (int reg = 0; reg < 4; ++reg) {
            float v = acc[ct][reg];
            float pv = __shfl_xor(v, 1, 64);
            int node = nbase + quad * 4 + reg;
            if (!(col & 1) && node < N_NODES)
                featb[(size_t)node * 64 + ct * 8 + (col >> 1)] = pack_bf2(v, pv);
        }
    }
    float alv[8], arv[8];
    #pragma unroll
    for (int ct = 0; ct < 8; ++ct) {
        alv[ct] = al[ct * 16 + col];
        arv[ct] = ar[ct * 16 + col];
    }
    #pragma unroll
    for (int reg = 0; reg < 4; ++reg) {
        int node = nbase + quad * 4 + reg;
        #pragma unroll
        for (int hd = 0; hd < 4; ++hd) {
            float pl = acc[2 * hd][reg] * alv[2 * hd] + acc[2 * hd + 1][reg] * alv[2 * hd + 1];
            float pr = acc[2 * hd][reg] * arv[2 * hd] + acc[2 * hd + 1][reg] * arv[2 * hd + 1];
            #pragma unroll
            for (int off = 1; off < 16; off <<= 1) {
                pl += __shfl_xor(pl, off, 64);
                pr += __shfl_xor(pr, off, 64);
            }
            if (col == hd && node < N_NODES) {
                el[node * 4 + hd] = pl * LOG2E;
                er[node * 4 + hd] = pr * LOG2E;
            }
        }
    }
}

__global__ __launch_bounds__(256)
void feat_kernel(const unsigned* __restrict__ hin, const int* __restrict__ wid,
                 const unsigned* __restrict__ wf,
                 const float* __restrict__ al, const float* __restrict__ ar,
                 unsigned* __restrict__ featb, float* __restrict__ el,
                 float* __restrict__ er) {
    feat_body(blockIdx.x, hin, wid, wf, al, ar, featb, el, er);
}

// scatter (CSR finalize, no atomics) fused with full layer-0 feat (R7 structure).
__global__ __launch_bounds__(256)
void scatter_feat0_kernel(const int* __restrict__ src, const int* __restrict__ dst,
                          const int* __restrict__ rank, const int* __restrict__ row_start,
                          int* __restrict__ csr_src,
                          const unsigned* __restrict__ embb, const int* __restrict__ wid,
                          const unsigned* __restrict__ wf0,
                          const float* __restrict__ al0, const float* __restrict__ ar0,
                          unsigned* __restrict__ featb, float* __restrict__ el,
                          float* __restrict__ er) {
    if (blockIdx.x < EDGE_NB) {
        scatter_body(blockIdx.x, src, dst, rank, row_start, csr_src);
    } else {
        feat_body(blockIdx.x - EDGE_NB, embb, wid, wf0, al0, ar0, featb, el, er);
    }
}

// Fused softmax + aggregation + ELU. One 64-lane wave per dst node.
// 16 lanes per edge, 8-edge main loop (R7-proven; 16-edge unroll regressed).
template<int OUT_BF16>
__global__ void gat_aggregate_t(const int* __restrict__ row_start, const int* __restrict__ csr_src,
                                const unsigned* __restrict__ featb, const float* __restrict__ el,
                                const float* __restrict__ er, float* __restrict__ houtf,
                                unsigned* __restrict__ houtb) {
    int lane = threadIdx.x & 63;
    int d = blockIdx.x * 4 + (threadIdx.x >> 6);
    int beg = row_start[d], end = row_start[d + 1];
    int eg = lane >> 4;          // edge slot 0..3
    int li = lane & 15;          // channel group: channels [8li, 8li+8)
    int hc = li >> 2;            // head of these channels
    float er_h = er[d * 4 + hc];
    float a0 = 0.f, a1 = 0.f, a2 = 0.f, a3 = 0.f;
    float a4 = 0.f, a5 = 0.f, a6 = 0.f, a7 = 0.f;
    float dsum = 0.f;
    int b8 = beg + ((end - beg) & ~7);
    for (int base = beg; base < b8; base += 8) {
        int ea = base + eg, eb = base + 4 + eg;
        int sa = csr_src[ea];
        int sb = csr_src[eb];
        float la = el[sa * 4 + hc];
        float lb = el[sb * 4 + hc];
        uint4 pa = *(const uint4*)(featb + (size_t)sa * 64 + li * 4);
        uint4 pb = *(const uint4*)(featb + (size_t)sb * 64 + li * 4);
        float va = la + er_h; va = fmaxf(va, NEG_SLOPE * va);
        float vb = lb + er_h; vb = fmaxf(vb, NEG_SLOPE * vb);
        float xa = exp2f(va), xb = exp2f(vb);
        dsum += xa + xb;
        a0 += __uint_as_float(pa.x << 16) * xa;
        a1 += __uint_as_float(pa.x & 0xFFFF0000u) * xa;
        a2 += __uint_as_float(pa.y << 16) * xa;
        a3 += __uint_as_float(pa.y & 0xFFFF0000u) * xa;
        a4 += __uint_as_float(pa.z << 16) * xa;
        a5 += __uint_as_float(pa.z & 0xFFFF0000u) * xa;
        a6 += __uint_as_float(pa.w << 16) * xa;
        a7 += __uint_as_float(pa.w & 0xFFFF0000u) * xa;
        a0 += __uint_as_float(pb.x << 16) * xb;
        a1 += __uint_as_float(pb.x & 0xFFFF0000u) * xb;
        a2 += __uint_as_float(pb.y << 16) * xb;
        a3 += __uint_as_float(pb.y & 0xFFFF0000u) * xb;
        a4 += __uint_as_float(pb.z << 16) * xb;
        a5 += __uint_as_float(pb.z & 0xFFFF0000u) * xb;
        a6 += __uint_as_float(pb.w << 16) * xb;
        a7 += __uint_as_float(pb.w & 0xFFFF0000u) * xb;
    }
    for (int ee = b8 + eg; ee < end; ee += 4) {
        int s = csr_src[ee];
        float lv = el[s * 4 + hc];
        uint4 pv = *(const uint4*)(featb + (size_t)s * 64 + li * 4);
        float v = lv + er_h; v = fmaxf(v, NEG_SLOPE * v);
        float x = exp2f(v);
        dsum += x;
        a0 += __uint_as_float(pv.x << 16) * x;
        a1 += __uint_as_float(pv.x & 0xFFFF0000u) * x;
        a2 += __uint_as_float(pv.y << 16) * x;
        a3 += __uint_as_float(pv.y & 0xFFFF0000u) * x;
        a4 += __uint_as_float(pv.z << 16) * x;
        a5 += __uint_as_float(pv.z & 0xFFFF0000u) * x;
        a6 += __uint_as_float(pv.w << 16) * x;
        a7 += __uint_as_float(pv.w & 0xFFFF0000u) * x;
    }
    #pragma unroll
    for (int off = 16; off < 64; off <<= 1) {
        a0 += __shfl_xor(a0, off, 64);
        a1 += __shfl_xor(a1, off, 64);
        a2 += __shfl_xor(a2, off, 64);
        a3 += __shfl_xor(a3, off, 64);
        a4 += __shfl_xor(a4, off, 64);
        a5 += __shfl_xor(a5, off, 64);
        a6 += __shfl_xor(a6, off, 64);
        a7 += __shfl_xor(a7, off, 64);
        dsum += __shfl_xor(dsum, off, 64);
    }
    if (eg == 0) {
        float inv = 1.f / (dsum + 1e-10f);
        float o0 = elu_fast(a0 * inv), o1 = elu_fast(a1 * inv);
        float o2 = elu_fast(a2 * inv), o3 = elu_fast(a3 * inv);
        float o4 = elu_fast(a4 * inv), o5 = elu_fast(a5 * inv);
        float o6 = elu_fast(a6 * inv), o7 = elu_fast(a7 * inv);
        if (OUT_BF16) {
            uint4 wv;
            wv.x = pack_bf2(o0, o1);
            wv.y = pack_bf2(o2, o3);
            wv.z = pack_bf2(o4, o5);
            wv.w = pack_bf2(o6, o7);
            ((uint4*)(houtb + (size_t)d * 64))[li] = wv;
        } else {
            float4* op = (float4*)(houtf + (size_t)d * 128);
            float4 w0 = {o0, o1, o2, o3};
            float4 w1 = {o4, o5, o6, o7};
            op[li * 2] = w0;
            op[li * 2 + 1] = w1;
        }
    }
}

// ---------------- pooling / loss ----------------

__global__ void pool_kernel(const int* __restrict__ gid, const float* __restrict__ h,
                            unsigned* __restrict__ pkeys) {
    int t = threadIdx.x;
    int c = t & 127;
    int par = t >> 7;              // 0/1
    int n0 = blockIdx.x * POOL_CHUNK;
    float m = 0.f;
    int cur_g = -1;
    for (int n = n0 + par; n < n0 + POOL_CHUNK; n += 2) {
        int g = gid[n];
        if (g != cur_g) {
            if (cur_g >= 0) atomicMax(&pkeys[cur_g * 128 + c], fkey(m));
            cur_g = g;
            m = -3.0e38f;
        }
        m = fmaxf(m, h[(size_t)n * 128 + c]);
    }
    if (cur_g >= 0) atomicMax(&pkeys[cur_g * 128 + c], fkey(m));
}

// logits + loss fused: one block, 4 waves.
__global__ void logits_final_kernel(const unsigned* __restrict__ pkeys,
                                    const float* __restrict__ w, const float* __restrict__ bptr,
                                    const float* __restrict__ y, float* __restrict__ out) {
    __shared__ float slog[N_GRAPHS];
    int t = threadIdx.x;
    int wv = t >> 6, lane = t & 63;
    float b = bptr[0];
    #pragma unroll
    for (int k = 0; k < 16; ++k) {
        int g = wv * 16 + k;
        float sum = 0.f;
        #pragma unroll
        for (int c0 = 0; c0 < 128; c0 += 64) {
            int c = c0 + lane;
            unsigned kk = pkeys[g * 128 + c];
            float v = (kk == 0u) ? 0.f : kval(kk);
            sum += v * w[c];
        }
        #pragma unroll
        for (int off = 32; off; off >>= 1) sum += __shfl_down(sum, off, 64);
        if (lane == 0) slog[g] = sum + b;
    }
    __syncthreads();
    if (t < N_GRAPHS) {
        float l = slog[t];
        float term = fmaxf(l, 0.f) - l * y[t] + log1pf(expf(-fabsf(l)));
        float s = term;
        #pragma unroll
        for (int off = 32; off; off >>= 1) s += __shfl_down(s, off, 64);
        out[1 + t] = 1.f / (1.f + expf(-l));
        if (t == 0) out[0] = s * (1.f / 64.f);
    }
}

extern "C" void kernel_launch(void* const* d_in, const int* in_sizes, int n_in,
                              void* d_out, int out_size, void* d_ws, size_t ws_size,
                              hipStream_t stream) {
    const int* word_ids  = (const int*)d_in[0];
    const int* esrc      = (const int*)d_in[1];
    const int* edst      = (const int*)d_in[2];
    const int* gid       = (const int*)d_in[3];
    const float* y_data  = (const float*)d_in[4];
    const float* emb     = (const float*)d_in[5];
    const float* W0      = (const float*)d_in[6];
    const float* al0     = (const float*)d_in[7];
    const float* ar0     = (const float*)d_in[8];
    const float* W1      = (const float*)d_in[9];
    const float* al1     = (const float*)d_in[10];
    const float* ar1     = (const float*)d_in[11];
    const float* out_w   = (const float*)d_in[12];
    const float* out_b   = (const float*)d_in[13];
    float* out = (float*)d_out;

    // workspace layout (float offsets)
    float* ws = (float*)d_ws;
    unsigned* featb  = (unsigned*)ws;                // N*64 uints = 3,200,000
    unsigned* hb     = (unsigned*)(ws + 3200000);    // N*64 uints (bf16 layer0 out)
    float*    hout   = ws + 6400000;                 // N*128 f32 (layer1 out)
    float*    el     = ws + 12800000;                // 200,000
    float*    er     = ws + 13000000;                // 200,000
    int*      row_st = (int*)(ws + 13200000);        // 50,001 (pad to 50,004)
    int*      deg    = (int*)(ws + 13250004);        // 50,000
    int*      rank   = (int*)(ws + 13300004);        // 800,000
    int*      csrsrc = (int*)(ws + 14100004);        // 800,000
    int*      partial= (int*)(ws + 14900004);        // 196 (pad to 200)
    unsigned* pkeys  = (unsigned*)(ws + 14900204);   // 8,192
    unsigned* wf0    = (unsigned*)(ws + 14908396);   // 8,192 uints (16B-aligned)
    unsigned* wf1    = (unsigned*)(ws + 14916588);   // 8,192 uints
    unsigned* embb   = (unsigned*)(ws + 14924780);   // VOCAB*64 uints (16B-aligned)

    // prep (W-frags, emb->bf16 pack, deg/pkeys zero) then CSR counting
    prep_kernel<<<16 + SCAN_NB + 32 + EMB_NB, 256, 0, stream>>>(
        W0, W1, emb, wf0, wf1, embb, deg, pkeys);
    hist_kernel<<<EDGE_NB, 256, 0, stream>>>(edst, deg, rank);
    partial_kernel<<<SCAN_NB, 256, 0, stream>>>(deg, partial);
    csr_offsets_kernel<<<SCAN_NB, 256, 0, stream>>>(deg, partial, row_st);

    // CSR scatter (rank-based, no atomics) fused with full layer-0 feat
    scatter_feat0_kernel<<<EDGE_NB + FEAT_NB, 256, 0, stream>>>(
        esrc, edst, rank, row_st, csrsrc, embb, word_ids, wf0, al0, ar0, featb, el, er);

    // layer 0 aggregate -> packed bf16 node features; layer 1
    gat_aggregate_t<1><<<12500, 256, 0, stream>>>(row_st, csrsrc, featb, el, er, nullptr, hb);
    feat_kernel<<<FEAT_NB, 256, 0, stream>>>(hb, nullptr, wf1, al1, ar1, featb, el, er);
    gat_aggregate_t<0><<<12500, 256, 0, stream>>>(row_st, csrsrc, featb, el, er, hout, nullptr);

    pool_kernel<<<POOL_NB, 256, 0, stream>>>(gid, hout, pkeys);
    logits_final_kernel<<<1, 256, 0, stream>>>(pkeys, out_w, out_b, y_data, out);
}